// Round 1
// baseline (384.325 us; speedup 1.0000x reference)
//
#include <hip/hip_runtime.h>
#include <cstdint>
#include <cstddef>

// BasicViTNCA3D: 24^3 cells, C=128, 8 heads x dim16, MLP 512, 2 NCA steps.
// All fp32. Workspace layout (floats):
//   wy[N*128] | wqkv[N*384] | wo[N*128] | wy2[N*128] | wh1[N*512]  = 70.8 MB
#define NCELL 13824

// ---------------- Threefry-2x32 (JAX-compatible) ----------------
__device__ __forceinline__ void tf2x32(uint32_t k0, uint32_t k1,
                                       uint32_t x0, uint32_t x1,
                                       uint32_t& o0, uint32_t& o1) {
  uint32_t k2 = k0 ^ k1 ^ 0x1BD11BDAu;
  x0 += k0; x1 += k1;
#define TFR(r) { x0 += x1; x1 = (x1 << (r)) | (x1 >> (32 - (r))); x1 ^= x0; }
  TFR(13) TFR(15) TFR(26) TFR(6)   x0 += k1; x1 += k2 + 1u;
  TFR(17) TFR(29) TFR(16) TFR(24)  x0 += k2; x1 += k0 + 2u;
  TFR(13) TFR(15) TFR(26) TFR(6)   x0 += k0; x1 += k1 + 3u;
  TFR(17) TFR(29) TFR(16) TFR(24)  x0 += k1; x1 += k2 + 4u;
  TFR(13) TFR(15) TFR(26) TFR(6)   x0 += k2; x1 += k0 + 5u;
#undef TFR
  o0 = x0; o1 = x1;
}

// ---------------- K1: pos-enc + LN1 + qkv GEMM ----------------
__global__ __launch_bounds__(256) void nca_k1(
    const float* __restrict__ x, const float* __restrict__ ln1s,
    const float* __restrict__ ln1b, const float* __restrict__ Wqkv,
    float* __restrict__ wy, float* __restrict__ wqkv,
    const int* __restrict__ steps, int s) {
  if (s >= *steps) return;
  __shared__ float ly[32][132];
  __shared__ float lmean[32], lrstd[32];
  const int t = threadIdx.x;
  const int base = blockIdx.x * 32;
  // load x rows, overwrite ch126/127 with positional encoding; keep y for residual
  #pragma unroll
  for (int i = 0; i < 16; ++i) {
    int idx = i * 256 + t;
    int r = idx >> 7, c = idx & 127;
    int n = base + r;
    float v;
    if (c < 126) {
      v = x[(size_t)n * 128 + c];
    } else {
      int dd = n % 24, ww = (n / 24) % 24, hh = n / 576;
      if (c == 126)
        v = sinf((float)hh) + sinf(0.01f * (float)ww) + sinf(0.0001f * (float)dd);
      else
        v = cosf((float)hh) + cosf(0.01f * (float)ww) + cosf(0.0001f * (float)dd);
    }
    ly[r][c] = v;
    wy[(size_t)n * 128 + c] = v;
  }
  __syncthreads();
  { // LN stats: 8 threads/row
    int r = t >> 3, j = t & 7;
    float s1 = 0.f, s2 = 0.f;
    #pragma unroll
    for (int cc = 0; cc < 16; ++cc) { float v = ly[r][j * 16 + cc]; s1 += v; s2 += v * v; }
    #pragma unroll
    for (int off = 1; off < 8; off <<= 1) { s1 += __shfl_xor(s1, off); s2 += __shfl_xor(s2, off); }
    if (j == 0) {
      float m = s1 * (1.f / 128.f);
      float var = s2 * (1.f / 128.f) - m * m;
      lmean[r] = m; lrstd[r] = rsqrtf(var + 1e-5f);
    }
  }
  __syncthreads();
  #pragma unroll
  for (int i = 0; i < 16; ++i) {
    int idx = i * 256 + t;
    int r = idx >> 7, c = idx & 127;
    ly[r][c] = (ly[r][c] - lmean[r]) * lrstd[r] * ln1s[c] + ln1b[c];
  }
  __syncthreads();
  // GEMM: [32x128] @ [128x384] -> qkv
  const int ct = t & 63, rg = t >> 6;
  float acc[8][6];
  #pragma unroll
  for (int rr = 0; rr < 8; ++rr)
    #pragma unroll
    for (int cc = 0; cc < 6; ++cc) acc[rr][cc] = 0.f;
  for (int k = 0; k < 128; ++k) {
    float a[8];
    #pragma unroll
    for (int rr = 0; rr < 8; ++rr) a[rr] = ly[rg * 8 + rr][k];
    #pragma unroll
    for (int cc = 0; cc < 6; ++cc) {
      float wk = Wqkv[k * 384 + cc * 64 + ct];
      #pragma unroll
      for (int rr = 0; rr < 8; ++rr) acc[rr][cc] += a[rr] * wk;
    }
  }
  #pragma unroll
  for (int rr = 0; rr < 8; ++rr) {
    size_t n = base + rg * 8 + rr;
    #pragma unroll
    for (int cc = 0; cc < 6; ++cc)
      wqkv[n * 384 + cc * 64 + ct] = acc[rr][cc];
  }
}

// ---------------- K2: 27-neighbor local attention ----------------
__global__ __launch_bounds__(256) void nca_k2(
    const float* __restrict__ qkv, float* __restrict__ o,
    const int* __restrict__ steps, int s) {
  if (s >= *steps) return;
  const int t = threadIdx.x;
  const int nloc = t >> 3, head = t & 7;
  const int n = blockIdx.x * 32 + nloc;
  const int dd = n % 24, ww = (n / 24) % 24, hh = n / 576;
  const float* qr = qkv + (size_t)n * 384 + head * 16;
  float q[16];
  #pragma unroll
  for (int j = 0; j < 4; ++j) {
    float4 v = ((const float4*)qr)[j];
    q[j*4] = v.x; q[j*4+1] = v.y; q[j*4+2] = v.z; q[j*4+3] = v.w;
  }
  float logits[27];
  int idx = 0;
  #pragma unroll
  for (int di = -1; di <= 1; ++di)
  #pragma unroll
  for (int dj = -1; dj <= 1; ++dj)
  #pragma unroll
  for (int dk = -1; dk <= 1; ++dk) {
    int h2 = hh + di, w2 = ww + dj, d2 = dd + dk;
    bool ok = ((unsigned)h2 < 24u) && ((unsigned)w2 < 24u) && ((unsigned)d2 < 24u);
    float dot = 0.f;
    if (ok) {
      const float* kr = qkv + (size_t)((h2 * 24 + w2) * 24 + d2) * 384 + 128 + head * 16;
      #pragma unroll
      for (int j = 0; j < 4; ++j) {
        float4 v = ((const float4*)kr)[j];
        dot += q[j*4]*v.x + q[j*4+1]*v.y + q[j*4+2]*v.z + q[j*4+3]*v.w;
      }
      dot *= 0.25f; // SCALE = 16^-0.5
    }
    logits[idx++] = dot; // OOB -> logit 0 (zero-padded localize)
  }
  float m = logits[0];
  #pragma unroll
  for (int j = 1; j < 27; ++j) m = fmaxf(m, logits[j]);
  float den = 0.f;
  #pragma unroll
  for (int j = 0; j < 27; ++j) { logits[j] = expf(logits[j] - m); den += logits[j]; }
  float acc[16];
  #pragma unroll
  for (int j = 0; j < 16; ++j) acc[j] = 0.f;
  idx = 0;
  #pragma unroll
  for (int di = -1; di <= 1; ++di)
  #pragma unroll
  for (int dj = -1; dj <= 1; ++dj)
  #pragma unroll
  for (int dk = -1; dk <= 1; ++dk) {
    int h2 = hh + di, w2 = ww + dj, d2 = dd + dk;
    bool ok = ((unsigned)h2 < 24u) && ((unsigned)w2 < 24u) && ((unsigned)d2 < 24u);
    if (ok) {
      const float* vr = qkv + (size_t)((h2 * 24 + w2) * 24 + d2) * 384 + 256 + head * 16;
      float wgt = logits[idx];
      #pragma unroll
      for (int j = 0; j < 4; ++j) {
        float4 v = ((const float4*)vr)[j];
        acc[j*4]   += wgt * v.x; acc[j*4+1] += wgt * v.y;
        acc[j*4+2] += wgt * v.z; acc[j*4+3] += wgt * v.w;
      }
    }
    ++idx;
  }
  float inv = 1.f / den;
  float* orow = o + (size_t)n * 128 + head * 16;
  #pragma unroll
  for (int j = 0; j < 4; ++j) {
    float4 v;
    v.x = acc[j*4] * inv; v.y = acc[j*4+1] * inv;
    v.z = acc[j*4+2] * inv; v.w = acc[j*4+3] * inv;
    ((float4*)orow)[j] = v;
  }
}

// ---------------- K3: out-proj + residual + LN2 + FF1 + GELU ----------------
__global__ __launch_bounds__(256) void nca_k3(
    const float* __restrict__ o, const float* __restrict__ wy,
    const float* __restrict__ Wout, const float* __restrict__ bout,
    const float* __restrict__ ln2s, const float* __restrict__ ln2b,
    const float* __restrict__ Wff1, const float* __restrict__ bff1,
    float* __restrict__ wy2, float* __restrict__ wh1,
    const int* __restrict__ steps, int s) {
  if (s >= *steps) return;
  __shared__ float lb[32][132];
  __shared__ float lmean[32], lrstd[32];
  const int t = threadIdx.x;
  const int base = blockIdx.x * 32;
  #pragma unroll
  for (int i = 0; i < 16; ++i) {
    int idx = i * 256 + t;
    int r = idx >> 7, c = idx & 127;
    lb[r][c] = o[(size_t)(base + r) * 128 + c];
  }
  __syncthreads();
  const int ct = t & 63, rg = t >> 6;
  float acc[8][2] = {};
  for (int k = 0; k < 128; ++k) {
    float a[8];
    #pragma unroll
    for (int rr = 0; rr < 8; ++rr) a[rr] = lb[rg * 8 + rr][k];
    #pragma unroll
    for (int cc = 0; cc < 2; ++cc) {
      float wk = Wout[k * 128 + cc * 64 + ct];
      #pragma unroll
      for (int rr = 0; rr < 8; ++rr) acc[rr][cc] += a[rr] * wk;
    }
  }
  __syncthreads();
  // y2 = o@Wout + b_out + y  -> global (residual for K4) + LDS (for LN2)
  #pragma unroll
  for (int rr = 0; rr < 8; ++rr) {
    int r = rg * 8 + rr;
    size_t n = base + r;
    #pragma unroll
    for (int cc = 0; cc < 2; ++cc) {
      int c = cc * 64 + ct;
      float v = acc[rr][cc] + bout[c] + wy[n * 128 + c];
      wy2[n * 128 + c] = v;
      lb[r][c] = v;
    }
  }
  __syncthreads();
  { // LN2 stats
    int r = t >> 3, j = t & 7;
    float s1 = 0.f, s2 = 0.f;
    #pragma unroll
    for (int cc = 0; cc < 16; ++cc) { float v = lb[r][j * 16 + cc]; s1 += v; s2 += v * v; }
    #pragma unroll
    for (int off = 1; off < 8; off <<= 1) { s1 += __shfl_xor(s1, off); s2 += __shfl_xor(s2, off); }
    if (j == 0) {
      float m = s1 * (1.f / 128.f);
      float var = s2 * (1.f / 128.f) - m * m;
      lmean[r] = m; lrstd[r] = rsqrtf(var + 1e-5f);
    }
  }
  __syncthreads();
  #pragma unroll
  for (int i = 0; i < 16; ++i) {
    int idx = i * 256 + t;
    int r = idx >> 7, c = idx & 127;
    lb[r][c] = (lb[r][c] - lmean[r]) * lrstd[r] * ln2s[c] + ln2b[c];
  }
  __syncthreads();
  // FF1: [32x128]@[128x512] + b -> exact GELU -> wh1
  float acc2[8][8] = {};
  for (int k = 0; k < 128; ++k) {
    float a[8];
    #pragma unroll
    for (int rr = 0; rr < 8; ++rr) a[rr] = lb[rg * 8 + rr][k];
    #pragma unroll
    for (int cc = 0; cc < 8; ++cc) {
      float wk = Wff1[k * 512 + cc * 64 + ct];
      #pragma unroll
      for (int rr = 0; rr < 8; ++rr) acc2[rr][cc] += a[rr] * wk;
    }
  }
  #pragma unroll
  for (int rr = 0; rr < 8; ++rr) {
    size_t n = base + rg * 8 + rr;
    #pragma unroll
    for (int cc = 0; cc < 8; ++cc) {
      int c = cc * 64 + ct;
      float v = acc2[rr][cc] + bff1[c];
      v = 0.5f * v * (1.f + erff(v * 0.70710678118654752f));
      wh1[n * 512 + c] = v;
    }
  }
}

// ---------------- K4: FF2 + residual + LN3 + head + mask update ----------------
__global__ __launch_bounds__(256) void nca_k4(
    const float* __restrict__ h1, const float* __restrict__ wy2,
    const float* __restrict__ Wff2, const float* __restrict__ bff2,
    const float* __restrict__ ln3s, const float* __restrict__ ln3b,
    const float* __restrict__ Whead, const float* __restrict__ bhead,
    const float* __restrict__ xin, float* __restrict__ xout,
    const int* __restrict__ steps, int s) {
  if (s >= *steps) return;
  __shared__ float lh[16][516];
  __shared__ float ly3[16][132];
  __shared__ float lmean[16], lrstd[16], lmask[16];
  const int t = threadIdx.x;
  const int base = blockIdx.x * 16;
  #pragma unroll
  for (int i = 0; i < 32; ++i) {
    int idx = i * 256 + t;
    int r = idx >> 9, c = idx & 511;
    lh[r][c] = h1[(size_t)(base + r) * 512 + c];
  }
  __syncthreads();
  const int ct = t & 63, rg = t >> 6; // 4 row-groups x 4 rows
  float acc[4][2] = {};
  for (int k = 0; k < 512; ++k) {
    float a[4];
    #pragma unroll
    for (int rr = 0; rr < 4; ++rr) a[rr] = lh[rg * 4 + rr][k];
    #pragma unroll
    for (int cc = 0; cc < 2; ++cc) {
      float wk = Wff2[k * 128 + cc * 64 + ct];
      #pragma unroll
      for (int rr = 0; rr < 4; ++rr) acc[rr][cc] += a[rr] * wk;
    }
  }
  #pragma unroll
  for (int rr = 0; rr < 4; ++rr) {
    int r = rg * 4 + rr;
    size_t n = base + r;
    #pragma unroll
    for (int cc = 0; cc < 2; ++cc) {
      int c = cc * 64 + ct;
      ly3[r][c] = acc[rr][cc] + bff2[c] + wy2[n * 128 + c];
    }
  }
  // per-cell stochastic mask: JAX threefry (partitionable random_bits)
  if (t < 16) {
    uint32_t kk0, kk1, b0, b1;
    tf2x32(0u, 42u, 0u, (uint32_t)s, kk0, kk1);          // fold_in(key(42), s)
    tf2x32(kk0, kk1, 0u, (uint32_t)(base + t), b0, b1);  // bits at flat index n
    uint32_t bits = b0 ^ b1;
    lmask[t] = ((bits >> 9) > 0x400000u) ? 1.0f : 0.0f;  // uniform > 0.5
  }
  __syncthreads();
  { // LN3 stats: 16 threads/row
    int r = t >> 4, j = t & 15;
    float s1 = 0.f, s2 = 0.f;
    #pragma unroll
    for (int cc = 0; cc < 8; ++cc) { float v = ly3[r][j * 8 + cc]; s1 += v; s2 += v * v; }
    #pragma unroll
    for (int off = 1; off < 16; off <<= 1) { s1 += __shfl_xor(s1, off); s2 += __shfl_xor(s2, off); }
    if (j == 0) {
      float m = s1 * (1.f / 128.f);
      float var = s2 * (1.f / 128.f) - m * m;
      lmean[r] = m; lrstd[r] = rsqrtf(var + 1e-5f);
    }
  }
  __syncthreads();
  #pragma unroll
  for (int i = 0; i < 8; ++i) {
    int idx = i * 256 + t;
    int r = idx >> 7, c = idx & 127;
    ly3[r][c] = (ly3[r][c] - lmean[r]) * lrstd[r] * ln3s[c] + ln3b[c];
  }
  __syncthreads();
  float acc2[4][2] = {};
  for (int k = 0; k < 128; ++k) {
    float a[4];
    #pragma unroll
    for (int rr = 0; rr < 4; ++rr) a[rr] = ly3[rg * 4 + rr][k];
    #pragma unroll
    for (int cc = 0; cc < 2; ++cc) {
      float wk = Whead[k * 128 + cc * 64 + ct];
      #pragma unroll
      for (int rr = 0; rr < 4; ++rr) acc2[rr][cc] += a[rr] * wk;
    }
  }
  #pragma unroll
  for (int rr = 0; rr < 4; ++rr) {
    int r = rg * 4 + rr;
    size_t n = base + r;
    float mk = lmask[r];
    #pragma unroll
    for (int cc = 0; cc < 2; ++cc) {
      int c = cc * 64 + ct;
      float dx = acc2[rr][cc] + bhead[c];
      xout[n * 128 + c] = xin[n * 128 + c] + dx * mk;
    }
  }
}

extern "C" void kernel_launch(void* const* d_in, const int* in_sizes, int n_in,
                              void* d_out, int out_size, void* d_ws, size_t ws_size,
                              hipStream_t stream) {
  const float* x0   = (const float*)d_in[0];
  const float* Wqkv = (const float*)d_in[1];
  const float* Wout = (const float*)d_in[2];
  const float* bout = (const float*)d_in[3];
  const float* ln1s = (const float*)d_in[4];
  const float* ln1b = (const float*)d_in[5];
  const float* Wff1 = (const float*)d_in[6];
  const float* bff1 = (const float*)d_in[7];
  const float* Wff2 = (const float*)d_in[8];
  const float* bff2 = (const float*)d_in[9];
  const float* ln2s = (const float*)d_in[10];
  const float* ln2b = (const float*)d_in[11];
  const float* ln3s = (const float*)d_in[12];
  const float* ln3b = (const float*)d_in[13];
  const float* Whead= (const float*)d_in[14];
  const float* bhead= (const float*)d_in[15];
  const int*   steps= (const int*)d_in[16];
  float* out = (float*)d_out;
  float* ws  = (float*)d_ws;

  float* wy   = ws;
  float* wqkv = wy   + (size_t)NCELL * 128;
  float* wo   = wqkv + (size_t)NCELL * 384;
  float* wy2  = wo   + (size_t)NCELL * 128;
  float* wh1  = wy2  + (size_t)NCELL * 128;

  // d_out serves as the x-state buffer between steps (in-place elementwise add
  // in K4 is safe). Hardcodes <=2 steps; each kernel no-ops if s >= *steps.
  for (int s = 0; s < 2; ++s) {
    const float* xin = (s == 0) ? x0 : out;
    nca_k1<<<dim3(432), dim3(256), 0, stream>>>(xin, ln1s, ln1b, Wqkv, wy, wqkv, steps, s);
    nca_k2<<<dim3(432), dim3(256), 0, stream>>>(wqkv, wo, steps, s);
    nca_k3<<<dim3(432), dim3(256), 0, stream>>>(wo, wy, Wout, bout, ln2s, ln2b,
                                                Wff1, bff1, wy2, wh1, steps, s);
    nca_k4<<<dim3(864), dim3(256), 0, stream>>>(wh1, wy2, Wff2, bff2, ln3s, ln3b,
                                                Whead, bhead, xin, out, steps, s);
  }
}

// Round 2
// 195.355 us; speedup vs baseline: 1.9673x; 1.9673x over previous
//
#include <hip/hip_runtime.h>
#include <cstdint>
#include <cstddef>

// BasicViTNCA3D: 24^3 cells, C=128, 8 heads x dim16, MLP 512, 2 NCA steps.
// GEMMs on bf16 MFMA (16x16x32), everything else fp32.
#define NCELL 13824

typedef short bf16x8 __attribute__((ext_vector_type(8)));  // 8 bf16 (4 VGPRs)
typedef float f32x4  __attribute__((ext_vector_type(4)));  // MFMA acc

__device__ __forceinline__ unsigned short f2bf(float x) {
  union { float f; uint32_t u; } c; c.f = x;
  uint32_t r = c.u + 0x7fffu + ((c.u >> 16) & 1u);  // round-to-nearest-even
  return (unsigned short)(r >> 16);
}

// A-fragment (16x32 tile, row = lane&15, k = (lane>>4)*8+j) from fp32 LDS row
__device__ __forceinline__ bf16x8 afrag_f32(const float* p) {
  float4 u0 = *(const float4*)p;
  float4 u1 = *(const float4*)(p + 4);
  bf16x8 a;
  a[0] = (short)f2bf(u0.x); a[1] = (short)f2bf(u0.y);
  a[2] = (short)f2bf(u0.z); a[3] = (short)f2bf(u0.w);
  a[4] = (short)f2bf(u1.x); a[5] = (short)f2bf(u1.y);
  a[6] = (short)f2bf(u1.z); a[7] = (short)f2bf(u1.w);
  return a;
}

// ---------------- Threefry-2x32 (JAX-compatible) ----------------
__device__ __forceinline__ void tf2x32(uint32_t k0, uint32_t k1,
                                       uint32_t x0, uint32_t x1,
                                       uint32_t& o0, uint32_t& o1) {
  uint32_t k2 = k0 ^ k1 ^ 0x1BD11BDAu;
  x0 += k0; x1 += k1;
#define TFR(r) { x0 += x1; x1 = (x1 << (r)) | (x1 >> (32 - (r))); x1 ^= x0; }
  TFR(13) TFR(15) TFR(26) TFR(6)   x0 += k1; x1 += k2 + 1u;
  TFR(17) TFR(29) TFR(16) TFR(24)  x0 += k2; x1 += k0 + 2u;
  TFR(13) TFR(15) TFR(26) TFR(6)   x0 += k0; x1 += k1 + 3u;
  TFR(17) TFR(29) TFR(16) TFR(24)  x0 += k1; x1 += k2 + 4u;
  TFR(13) TFR(15) TFR(26) TFR(6)   x0 += k2; x1 += k0 + 5u;
#undef TFR
  o0 = x0; o1 = x1;
}

// ---------------- weight pack: W[K][N] fp32 -> MFMA B-frag bf16 ----------------
// P[((nt*KT + kt)*64 + lane)*8 + j] = bf16(W[(kt*32 + (lane>>4)*8 + j)*N + nt*16 + (lane&15)])
__global__ __launch_bounds__(256) void packW(const float* __restrict__ W, int K, int N,
                                             unsigned short* __restrict__ P) {
  int f = blockIdx.x * 256 + threadIdx.x;
  int KT = K >> 5;
  int total = (N >> 4) * KT * 64;
  if (f >= total) return;
  int lane = f & 63;
  int ft = f >> 6;
  int kt = ft % KT, nt = ft / KT;
  int col = nt * 16 + (lane & 15);
  int k0 = kt * 32 + (lane >> 4) * 8;
  uint32_t w[4];
  #pragma unroll
  for (int p = 0; p < 4; ++p) {
    uint32_t lo = f2bf(W[(size_t)(k0 + 2 * p) * N + col]);
    uint32_t hi = f2bf(W[(size_t)(k0 + 2 * p + 1) * N + col]);
    w[p] = lo | (hi << 16);
  }
  uint4 v; v.x = w[0]; v.y = w[1]; v.z = w[2]; v.w = w[3];
  ((uint4*)P)[f] = v;
}

// ---------------- K1: pos-enc + LN1 + qkv GEMM (MFMA) ----------------
__global__ __launch_bounds__(256) void nca_k1(
    const float* __restrict__ x, const float* __restrict__ ln1s,
    const float* __restrict__ ln1b, const unsigned short* __restrict__ pQkv,
    float* __restrict__ wy, float* __restrict__ wqkv,
    const int* __restrict__ steps, int s) {
  if (s >= *steps) return;
  __shared__ float ly[16][132];
  __shared__ float lmean[16], lrstd[16];
  const int t = threadIdx.x;
  const int base = blockIdx.x * 16;
  #pragma unroll
  for (int i = 0; i < 8; ++i) {
    int idx = i * 256 + t;
    int r = idx >> 7, c = idx & 127;
    int n = base + r;
    float v;
    if (c < 126) {
      v = x[(size_t)n * 128 + c];
    } else {
      int dd = n % 24, ww = (n / 24) % 24, hh = n / 576;
      if (c == 126)
        v = sinf((float)hh) + sinf(0.01f * (float)ww) + sinf(0.0001f * (float)dd);
      else
        v = cosf((float)hh) + cosf(0.01f * (float)ww) + cosf(0.0001f * (float)dd);
    }
    ly[r][c] = v;
    wy[(size_t)n * 128 + c] = v;
  }
  __syncthreads();
  { // LN1 stats: 16 threads/row, 8 elems each
    int r = t >> 4, j = t & 15;
    float s1 = 0.f, s2 = 0.f;
    #pragma unroll
    for (int cc = 0; cc < 8; ++cc) { float v = ly[r][j * 8 + cc]; s1 += v; s2 += v * v; }
    #pragma unroll
    for (int off = 1; off < 16; off <<= 1) { s1 += __shfl_xor(s1, off); s2 += __shfl_xor(s2, off); }
    if (j == 0) {
      float m = s1 * (1.f / 128.f);
      float var = s2 * (1.f / 128.f) - m * m;
      lmean[r] = m; lrstd[r] = rsqrtf(var + 1e-5f);
    }
  }
  __syncthreads();
  #pragma unroll
  for (int i = 0; i < 8; ++i) {
    int idx = i * 256 + t;
    int r = idx >> 7, c = idx & 127;
    ly[r][c] = (ly[r][c] - lmean[r]) * lrstd[r] * ln1s[c] + ln1b[c];
  }
  __syncthreads();
  // GEMM 16x384, K=128: wave w handles coltiles w*6 .. w*6+5
  const int w = t >> 6, l = t & 63;
  bf16x8 a4[4];
  #pragma unroll
  for (int kt = 0; kt < 4; ++kt)
    a4[kt] = afrag_f32(&ly[l & 15][kt * 32 + (l >> 4) * 8]);
  f32x4 acc[6];
  #pragma unroll
  for (int q = 0; q < 6; ++q) acc[q] = (f32x4){0.f, 0.f, 0.f, 0.f};
  const bf16x8* B = (const bf16x8*)pQkv;
  #pragma unroll
  for (int kt = 0; kt < 4; ++kt) {
    #pragma unroll
    for (int q = 0; q < 6; ++q) {
      int nt = w * 6 + q;
      bf16x8 b = B[(nt * 4 + kt) * 64 + l];
      acc[q] = __builtin_amdgcn_mfma_f32_16x16x32_bf16(a4[kt], b, acc[q], 0, 0, 0);
    }
  }
  #pragma unroll
  for (int q = 0; q < 6; ++q) {
    int col = (w * 6 + q) * 16 + (l & 15);
    #pragma unroll
    for (int j = 0; j < 4; ++j)
      wqkv[(size_t)(base + (l >> 4) * 4 + j) * 384 + col] = acc[q][j];
  }
}

// ---------------- K2: 27-neighbor local attention (4 thr/(cell,head)) ----------------
__global__ __launch_bounds__(256) void nca_k2(
    const float* __restrict__ qkv, float* __restrict__ o,
    const int* __restrict__ steps, int s) {
  if (s >= *steps) return;
  const int t = threadIdx.x;
  const int cell = t >> 5, head = (t >> 2) & 7, sub = t & 3;
  const int n = blockIdx.x * 8 + cell;
  const int dd = n % 24, ww = (n / 24) % 24, hh = n / 576;
  const float4 q = *(const float4*)(qkv + (size_t)n * 384 + head * 16 + sub * 4);
  float logits[27];
  int idx = 0;
  #pragma unroll
  for (int di = -1; di <= 1; ++di)
  #pragma unroll
  for (int dj = -1; dj <= 1; ++dj)
  #pragma unroll
  for (int dk = -1; dk <= 1; ++dk) {
    int h2 = hh + di, w2 = ww + dj, d2 = dd + dk;
    bool ok = ((unsigned)h2 < 24u) && ((unsigned)w2 < 24u) && ((unsigned)d2 < 24u);
    float dot = 0.f;
    if (ok) {
      float4 kv = *(const float4*)(qkv + (size_t)((h2 * 24 + w2) * 24 + d2) * 384
                                   + 128 + head * 16 + sub * 4);
      dot = q.x * kv.x + q.y * kv.y + q.z * kv.z + q.w * kv.w;
    }
    dot += __shfl_xor(dot, 1);
    dot += __shfl_xor(dot, 2);
    logits[idx++] = dot * 0.25f;  // OOB lanes contribute 0 -> logit 0
  }
  float m = logits[0];
  #pragma unroll
  for (int j = 1; j < 27; ++j) m = fmaxf(m, logits[j]);
  float den = 0.f;
  #pragma unroll
  for (int j = 0; j < 27; ++j) { logits[j] = expf(logits[j] - m); den += logits[j]; }
  float ax = 0.f, ay = 0.f, az = 0.f, aw = 0.f;
  idx = 0;
  #pragma unroll
  for (int di = -1; di <= 1; ++di)
  #pragma unroll
  for (int dj = -1; dj <= 1; ++dj)
  #pragma unroll
  for (int dk = -1; dk <= 1; ++dk) {
    int h2 = hh + di, w2 = ww + dj, d2 = dd + dk;
    bool ok = ((unsigned)h2 < 24u) && ((unsigned)w2 < 24u) && ((unsigned)d2 < 24u);
    if (ok) {
      float4 vv = *(const float4*)(qkv + (size_t)((h2 * 24 + w2) * 24 + d2) * 384
                                   + 256 + head * 16 + sub * 4);
      float wgt = logits[idx];
      ax += wgt * vv.x; ay += wgt * vv.y; az += wgt * vv.z; aw += wgt * vv.w;
    }
    ++idx;
  }
  float inv = 1.f / den;
  float4 res; res.x = ax * inv; res.y = ay * inv; res.z = az * inv; res.w = aw * inv;
  *(float4*)(o + (size_t)n * 128 + head * 16 + sub * 4) = res;
}

// ---------------- K34: out-proj+res+LN2+FF1+GELU+FF2+res+LN3+head+mask ----------------
__global__ __launch_bounds__(256) void nca_k34(
    const float* __restrict__ o, const float* __restrict__ wy,
    const unsigned short* __restrict__ pOut, const float* __restrict__ bout,
    const float* __restrict__ ln2s, const float* __restrict__ ln2b,
    const unsigned short* __restrict__ pFF1, const float* __restrict__ bff1,
    const unsigned short* __restrict__ pFF2, const float* __restrict__ bff2,
    const float* __restrict__ ln3s, const float* __restrict__ ln3b,
    const unsigned short* __restrict__ pHead, const float* __restrict__ bhead,
    const float* __restrict__ xin, float* __restrict__ xout,
    const int* __restrict__ steps, int s) {
  if (s >= *steps) return;
  __shared__ float lbuf[16][132];           // o -> ln2(y2) -> y3 -> ln3(y3)
  __shared__ float ly2[16][132];            // y2 (residual for FF2)
  __shared__ unsigned short lh[16][520];    // GELU(FF1) bf16
  __shared__ float lmean[16], lrstd[16], lmask[16];
  const int t = threadIdx.x;
  const int base = blockIdx.x * 16;
  const int w = t >> 6, l = t & 63;
  const int lr = (l >> 4) * 4;              // D-frag row base
  const int lc = l & 15;                    // D-frag col within tile
  // stage attention output
  #pragma unroll
  for (int i = 0; i < 8; ++i) {
    int idx = i * 256 + t;
    int r = idx >> 7, c = idx & 127;
    lbuf[r][c] = o[(size_t)(base + r) * 128 + c];
  }
  if (t < 16) { // stochastic per-cell mask (JAX threefry, partitionable bits)
    uint32_t kk0, kk1, b0, b1;
    tf2x32(0u, 42u, 0u, (uint32_t)s, kk0, kk1);
    tf2x32(kk0, kk1, 0u, (uint32_t)(base + t), b0, b1);
    uint32_t bits = b0 ^ b1;
    lmask[t] = ((bits >> 9) > 0x400000u) ? 1.0f : 0.0f;
  }
  __syncthreads();
  // out-proj GEMM 16x128, K=128; wave w: coltiles w*2, w*2+1
  bf16x8 a4[4];
  #pragma unroll
  for (int kt = 0; kt < 4; ++kt)
    a4[kt] = afrag_f32(&lbuf[l & 15][kt * 32 + (l >> 4) * 8]);
  {
    f32x4 acc[2];
    acc[0] = (f32x4){0.f,0.f,0.f,0.f}; acc[1] = (f32x4){0.f,0.f,0.f,0.f};
    const bf16x8* B = (const bf16x8*)pOut;
    #pragma unroll
    for (int kt = 0; kt < 4; ++kt) {
      #pragma unroll
      for (int q = 0; q < 2; ++q) {
        int nt = w * 2 + q;
        bf16x8 b = B[(nt * 4 + kt) * 64 + l];
        acc[q] = __builtin_amdgcn_mfma_f32_16x16x32_bf16(a4[kt], b, acc[q], 0, 0, 0);
      }
    }
    __syncthreads();  // all frag reads of lbuf done everywhere
    #pragma unroll
    for (int q = 0; q < 2; ++q) {
      int col = (w * 2 + q) * 16 + lc;
      #pragma unroll
      for (int j = 0; j < 4; ++j) {
        int r = lr + j;
        float v = acc[q][j] + bout[col] + wy[(size_t)(base + r) * 128 + col];
        ly2[r][col] = v;
      }
    }
  }
  __syncthreads();
  { // LN2 stats
    int r = t >> 4, j = t & 15;
    float s1 = 0.f, s2 = 0.f;
    #pragma unroll
    for (int cc = 0; cc < 8; ++cc) { float v = ly2[r][j * 8 + cc]; s1 += v; s2 += v * v; }
    #pragma unroll
    for (int off = 1; off < 16; off <<= 1) { s1 += __shfl_xor(s1, off); s2 += __shfl_xor(s2, off); }
    if (j == 0) {
      float m = s1 * (1.f / 128.f);
      float var = s2 * (1.f / 128.f) - m * m;
      lmean[r] = m; lrstd[r] = rsqrtf(var + 1e-5f);
    }
  }
  __syncthreads();
  #pragma unroll
  for (int i = 0; i < 8; ++i) {
    int idx = i * 256 + t;
    int r = idx >> 7, c = idx & 127;
    lbuf[r][c] = (ly2[r][c] - lmean[r]) * lrstd[r] * ln2s[c] + ln2b[c];
  }
  __syncthreads();
  // FF1 GEMM 16x512, K=128; wave w: coltiles w*8 .. w*8+7; GELU -> lh bf16
  #pragma unroll
  for (int kt = 0; kt < 4; ++kt)
    a4[kt] = afrag_f32(&lbuf[l & 15][kt * 32 + (l >> 4) * 8]);
  {
    f32x4 acc[8];
    #pragma unroll
    for (int q = 0; q < 8; ++q) acc[q] = (f32x4){0.f,0.f,0.f,0.f};
    const bf16x8* B = (const bf16x8*)pFF1;
    #pragma unroll
    for (int kt = 0; kt < 4; ++kt) {
      #pragma unroll
      for (int q = 0; q < 8; ++q) {
        int nt = w * 8 + q;
        bf16x8 b = B[(nt * 4 + kt) * 64 + l];
        acc[q] = __builtin_amdgcn_mfma_f32_16x16x32_bf16(a4[kt], b, acc[q], 0, 0, 0);
      }
    }
    #pragma unroll
    for (int q = 0; q < 8; ++q) {
      int col = (w * 8 + q) * 16 + lc;
      #pragma unroll
      for (int j = 0; j < 4; ++j) {
        float v = acc[q][j] + bff1[col];
        v = 0.5f * v * (1.f + erff(v * 0.70710678118654752f));
        lh[lr + j][col] = f2bf(v);
      }
    }
  }
  __syncthreads();
  // FF2 GEMM 16x128, K=512; wave w: coltiles w*2, w*2+1
  f32x4 acc3[2];
  acc3[0] = (f32x4){0.f,0.f,0.f,0.f}; acc3[1] = (f32x4){0.f,0.f,0.f,0.f};
  {
    const bf16x8* B = (const bf16x8*)pFF2;
    #pragma unroll
    for (int kt = 0; kt < 16; ++kt) {
      bf16x8 a = *(const bf16x8*)&lh[l & 15][kt * 32 + (l >> 4) * 8];
      #pragma unroll
      for (int q = 0; q < 2; ++q) {
        int nt = w * 2 + q;
        bf16x8 b = B[(nt * 16 + kt) * 64 + l];
        acc3[q] = __builtin_amdgcn_mfma_f32_16x16x32_bf16(a, b, acc3[q], 0, 0, 0);
      }
    }
  }
  __syncthreads();  // lbuf (ln2 values) fully consumed by FF1 frags
  #pragma unroll
  for (int q = 0; q < 2; ++q) {
    int col = (w * 2 + q) * 16 + lc;
    #pragma unroll
    for (int j = 0; j < 4; ++j) {
      int r = lr + j;
      lbuf[r][col] = acc3[q][j] + bff2[col] + ly2[r][col];  // y3
    }
  }
  __syncthreads();
  { // LN3 stats
    int r = t >> 4, j = t & 15;
    float s1 = 0.f, s2 = 0.f;
    #pragma unroll
    for (int cc = 0; cc < 8; ++cc) { float v = lbuf[r][j * 8 + cc]; s1 += v; s2 += v * v; }
    #pragma unroll
    for (int off = 1; off < 16; off <<= 1) { s1 += __shfl_xor(s1, off); s2 += __shfl_xor(s2, off); }
    if (j == 0) {
      float m = s1 * (1.f / 128.f);
      float var = s2 * (1.f / 128.f) - m * m;
      lmean[r] = m; lrstd[r] = rsqrtf(var + 1e-5f);
    }
  }
  __syncthreads();
  #pragma unroll
  for (int i = 0; i < 8; ++i) {
    int idx = i * 256 + t;
    int r = idx >> 7, c = idx & 127;
    lbuf[r][c] = (lbuf[r][c] - lmean[r]) * lrstd[r] * ln3s[c] + ln3b[c];
  }
  __syncthreads();
  // head GEMM 16x128, K=128 -> dx; masked residual update
  #pragma unroll
  for (int kt = 0; kt < 4; ++kt)
    a4[kt] = afrag_f32(&lbuf[l & 15][kt * 32 + (l >> 4) * 8]);
  {
    f32x4 acc[2];
    acc[0] = (f32x4){0.f,0.f,0.f,0.f}; acc[1] = (f32x4){0.f,0.f,0.f,0.f};
    const bf16x8* B = (const bf16x8*)pHead;
    #pragma unroll
    for (int kt = 0; kt < 4; ++kt) {
      #pragma unroll
      for (int q = 0; q < 2; ++q) {
        int nt = w * 2 + q;
        bf16x8 b = B[(nt * 4 + kt) * 64 + l];
        acc[q] = __builtin_amdgcn_mfma_f32_16x16x32_bf16(a4[kt], b, acc[q], 0, 0, 0);
      }
    }
    #pragma unroll
    for (int q = 0; q < 2; ++q) {
      int col = (w * 2 + q) * 16 + lc;
      #pragma unroll
      for (int j = 0; j < 4; ++j) {
        int r = lr + j;
        size_t n = base + r;
        float dx = acc[q][j] + bhead[col];
        xout[n * 128 + col] = xin[n * 128 + col] + dx * lmask[r];
      }
    }
  }
}

extern "C" void kernel_launch(void* const* d_in, const int* in_sizes, int n_in,
                              void* d_out, int out_size, void* d_ws, size_t ws_size,
                              hipStream_t stream) {
  const float* x0   = (const float*)d_in[0];
  const float* Wqkv = (const float*)d_in[1];
  const float* Wout = (const float*)d_in[2];
  const float* bout = (const float*)d_in[3];
  const float* ln1s = (const float*)d_in[4];
  const float* ln1b = (const float*)d_in[5];
  const float* Wff1 = (const float*)d_in[6];
  const float* bff1 = (const float*)d_in[7];
  const float* Wff2 = (const float*)d_in[8];
  const float* bff2 = (const float*)d_in[9];
  const float* ln2s = (const float*)d_in[10];
  const float* ln2b = (const float*)d_in[11];
  const float* ln3s = (const float*)d_in[12];
  const float* ln3b = (const float*)d_in[13];
  const float* Whead= (const float*)d_in[14];
  const float* bhead= (const float*)d_in[15];
  const int*   steps= (const int*)d_in[16];
  float* out = (float*)d_out;
  float* ws  = (float*)d_ws;

  float* wy   = ws;                                    // N*128
  float* wqkv = wy + (size_t)NCELL * 128;              // N*384
  float* wo   = wqkv + (size_t)NCELL * 384;            // N*128
  unsigned short* pQkv = (unsigned short*)(wo + (size_t)NCELL * 128);
  unsigned short* pOut = pQkv + 128 * 384;
  unsigned short* pFF1 = pOut + 128 * 128;
  unsigned short* pFF2 = pFF1 + 128 * 512;
  unsigned short* pHead= pFF2 + 512 * 128;

  // pack weights to MFMA B-fragment layout (bf16), once per launch
  packW<<<dim3((24 * 4 * 64 + 255) / 256), dim3(256), 0, stream>>>(Wqkv, 128, 384, pQkv);
  packW<<<dim3((8 * 4 * 64 + 255) / 256),  dim3(256), 0, stream>>>(Wout, 128, 128, pOut);
  packW<<<dim3((32 * 4 * 64 + 255) / 256), dim3(256), 0, stream>>>(Wff1, 128, 512, pFF1);
  packW<<<dim3((8 * 16 * 64 + 255) / 256), dim3(256), 0, stream>>>(Wff2, 512, 128, pFF2);
  packW<<<dim3((8 * 4 * 64 + 255) / 256),  dim3(256), 0, stream>>>(Whead, 128, 128, pHead);

  for (int s = 0; s < 2; ++s) {
    const float* xin = (s == 0) ? x0 : out;
    nca_k1<<<dim3(864), dim3(256), 0, stream>>>(xin, ln1s, ln1b, pQkv, wy, wqkv, steps, s);
    nca_k2<<<dim3(1728), dim3(256), 0, stream>>>(wqkv, wo, steps, s);
    nca_k34<<<dim3(864), dim3(256), 0, stream>>>(wo, wy, pOut, bout, ln2s, ln2b,
                                                 pFF1, bff1, pFF2, bff2, ln3s, ln3b,
                                                 pHead, bhead, xin, out, steps, s);
  }
}

// Round 3
// 182.641 us; speedup vs baseline: 2.1043x; 1.0696x over previous
//
#include <hip/hip_runtime.h>
#include <cstdint>
#include <cstddef>

// BasicViTNCA3D: 24^3 cells, C=128, 8 heads x dim16, MLP 512, 2 NCA steps.
// GEMMs on bf16 MFMA (16x16x32); qkv stored bf16; residual stream fp32.
// 5 dispatches total: packAll + 2 x (k1: pe+LN1+qkv, k2f: attn+rest-of-block).
#define NCELL 13824

typedef short bf16x8 __attribute__((ext_vector_type(8)));  // 8 bf16 (4 VGPRs)
typedef float f32x4  __attribute__((ext_vector_type(4)));  // MFMA acc

__device__ __forceinline__ unsigned short f2bf(float x) {
  union { float f; uint32_t u; } c; c.f = x;
  uint32_t r = c.u + 0x7fffu + ((c.u >> 16) & 1u);  // RNE
  return (unsigned short)(r >> 16);
}
__device__ __forceinline__ float bf2f(unsigned short b) {
  union { uint32_t u; float f; } c; c.u = ((uint32_t)b) << 16; return c.f;
}
// 8 consecutive bf16 -> 8 floats (one 16B load)
__device__ __forceinline__ void bf8_to_f(const unsigned short* p, float* f) {
  uint4 v = *(const uint4*)p;
  union { uint32_t u; float x; } c;
  c.u = v.x << 16; f[0] = c.x;  c.u = v.x & 0xffff0000u; f[1] = c.x;
  c.u = v.y << 16; f[2] = c.x;  c.u = v.y & 0xffff0000u; f[3] = c.x;
  c.u = v.z << 16; f[4] = c.x;  c.u = v.z & 0xffff0000u; f[5] = c.x;
  c.u = v.w << 16; f[6] = c.x;  c.u = v.w & 0xffff0000u; f[7] = c.x;
}

// A-fragment (16x32 tile, row = lane&15, k = (lane>>4)*8+j) from fp32 LDS row
__device__ __forceinline__ bf16x8 afrag_f32(const float* p) {
  float4 u0 = *(const float4*)p;
  float4 u1 = *(const float4*)(p + 4);
  bf16x8 a;
  a[0] = (short)f2bf(u0.x); a[1] = (short)f2bf(u0.y);
  a[2] = (short)f2bf(u0.z); a[3] = (short)f2bf(u0.w);
  a[4] = (short)f2bf(u1.x); a[5] = (short)f2bf(u1.y);
  a[6] = (short)f2bf(u1.z); a[7] = (short)f2bf(u1.w);
  return a;
}

// ---------------- Threefry-2x32 (JAX-compatible) ----------------
__device__ __forceinline__ void tf2x32(uint32_t k0, uint32_t k1,
                                       uint32_t x0, uint32_t x1,
                                       uint32_t& o0, uint32_t& o1) {
  uint32_t k2 = k0 ^ k1 ^ 0x1BD11BDAu;
  x0 += k0; x1 += k1;
#define TFR(r) { x0 += x1; x1 = (x1 << (r)) | (x1 >> (32 - (r))); x1 ^= x0; }
  TFR(13) TFR(15) TFR(26) TFR(6)   x0 += k1; x1 += k2 + 1u;
  TFR(17) TFR(29) TFR(16) TFR(24)  x0 += k2; x1 += k0 + 2u;
  TFR(13) TFR(15) TFR(26) TFR(6)   x0 += k0; x1 += k1 + 3u;
  TFR(17) TFR(29) TFR(16) TFR(24)  x0 += k1; x1 += k2 + 4u;
  TFR(13) TFR(15) TFR(26) TFR(6)   x0 += k2; x1 += k0 + 5u;
#undef TFR
  o0 = x0; o1 = x1;
}

// pos-enc values for channels 126/127 at flat cell n
__device__ __forceinline__ float pe_val(int n, int c) {
  int dd = n % 24, ww = (n / 24) % 24, hh = n / 576;
  if (c == 126)
    return sinf((float)hh) + sinf(0.01f * (float)ww) + sinf(0.0001f * (float)dd);
  return cosf((float)hh) + cosf(0.01f * (float)ww) + cosf(0.0001f * (float)dd);
}

// ---------------- packAll: all 5 weights -> MFMA B-frag bf16, one kernel ----------
// P[((nt*KT + kt)*64 + lane)*8 + j] = bf16(W[(kt*32 + (lane>>4)*8 + j)*N + nt*16 + (lane&15)])
__device__ __forceinline__ void packOne(const float* __restrict__ W, int K, int N,
                                        unsigned short* __restrict__ P, int f) {
  int KT = K >> 5;
  int lane = f & 63;
  int ft = f >> 6;
  int kt = ft % KT, nt = ft / KT;
  int col = nt * 16 + (lane & 15);
  int k0 = kt * 32 + (lane >> 4) * 8;
  uint32_t w[4];
  #pragma unroll
  for (int p = 0; p < 4; ++p) {
    uint32_t lo = f2bf(W[(size_t)(k0 + 2 * p) * N + col]);
    uint32_t hi = f2bf(W[(size_t)(k0 + 2 * p + 1) * N + col]);
    w[p] = lo | (hi << 16);
  }
  uint4 v; v.x = w[0]; v.y = w[1]; v.z = w[2]; v.w = w[3];
  ((uint4*)P)[f] = v;
}

__global__ __launch_bounds__(256) void packAll(
    const float* __restrict__ Wqkv, const float* __restrict__ Wout,
    const float* __restrict__ Wff1, const float* __restrict__ Wff2,
    const float* __restrict__ Whead,
    unsigned short* __restrict__ pQkv, unsigned short* __restrict__ pOut,
    unsigned short* __restrict__ pFF1, unsigned short* __restrict__ pFF2,
    unsigned short* __restrict__ pHead) {
  int f = blockIdx.x * 256 + threadIdx.x;
  if (f < 6144)        packOne(Wqkv, 128, 384, pQkv, f);
  else if (f < 8192)   packOne(Wout, 128, 128, pOut, f - 6144);
  else if (f < 16384)  packOne(Wff1, 128, 512, pFF1, f - 8192);
  else if (f < 24576)  packOne(Wff2, 512, 128, pFF2, f - 16384);
  else if (f < 26624)  packOne(Whead, 128, 128, pHead, f - 24576);
}

// ---------------- K1: pos-enc + LN1 + qkv GEMM -> bf16 qkv ----------------
__global__ __launch_bounds__(256) void nca_k1(
    const float* __restrict__ x, const float* __restrict__ ln1s,
    const float* __restrict__ ln1b, const unsigned short* __restrict__ pQkv,
    unsigned short* __restrict__ wqkv,
    const int* __restrict__ steps, int s) {
  if (s >= *steps) return;
  __shared__ float ly[16][132];
  __shared__ float lmean[16], lrstd[16];
  const int t = threadIdx.x;
  const int base = blockIdx.x * 16;
  #pragma unroll
  for (int i = 0; i < 8; ++i) {
    int idx = i * 256 + t;
    int r = idx >> 7, c = idx & 127;
    int n = base + r;
    ly[r][c] = (c < 126) ? x[(size_t)n * 128 + c] : pe_val(n, c);
  }
  __syncthreads();
  { // LN1 stats: 16 threads/row, 8 elems each
    int r = t >> 4, j = t & 15;
    float s1 = 0.f, s2 = 0.f;
    #pragma unroll
    for (int cc = 0; cc < 8; ++cc) { float v = ly[r][j * 8 + cc]; s1 += v; s2 += v * v; }
    #pragma unroll
    for (int off = 1; off < 16; off <<= 1) { s1 += __shfl_xor(s1, off); s2 += __shfl_xor(s2, off); }
    if (j == 0) {
      float m = s1 * (1.f / 128.f);
      float var = s2 * (1.f / 128.f) - m * m;
      lmean[r] = m; lrstd[r] = rsqrtf(var + 1e-5f);
    }
  }
  __syncthreads();
  #pragma unroll
  for (int i = 0; i < 8; ++i) {
    int idx = i * 256 + t;
    int r = idx >> 7, c = idx & 127;
    ly[r][c] = (ly[r][c] - lmean[r]) * lrstd[r] * ln1s[c] + ln1b[c];
  }
  __syncthreads();
  // GEMM 16x384, K=128: wave w -> coltiles w*6 .. w*6+5
  const int w = t >> 6, l = t & 63;
  bf16x8 a4[4];
  #pragma unroll
  for (int kt = 0; kt < 4; ++kt)
    a4[kt] = afrag_f32(&ly[l & 15][kt * 32 + (l >> 4) * 8]);
  f32x4 acc[6];
  #pragma unroll
  for (int q = 0; q < 6; ++q) acc[q] = (f32x4){0.f, 0.f, 0.f, 0.f};
  const bf16x8* B = (const bf16x8*)pQkv;
  #pragma unroll
  for (int kt = 0; kt < 4; ++kt) {
    #pragma unroll
    for (int q = 0; q < 6; ++q) {
      int nt = w * 6 + q;
      bf16x8 b = B[(nt * 4 + kt) * 64 + l];
      acc[q] = __builtin_amdgcn_mfma_f32_16x16x32_bf16(a4[kt], b, acc[q], 0, 0, 0);
    }
  }
  #pragma unroll
  for (int q = 0; q < 6; ++q) {
    int col = (w * 6 + q) * 16 + (l & 15);
    #pragma unroll
    for (int j = 0; j < 4; ++j)
      wqkv[(size_t)(base + (l >> 4) * 4 + j) * 384 + col] = f2bf(acc[q][j]);
  }
}

// ---- K2f: attn + out-proj + res + LN2 + FF1 + GELU + FF2 + res + LN3 + head + mask ----
__global__ __launch_bounds__(256) void nca_k2f(
    const unsigned short* __restrict__ qkv,
    const unsigned short* __restrict__ pOut, const float* __restrict__ bout,
    const float* __restrict__ ln2s, const float* __restrict__ ln2b,
    const unsigned short* __restrict__ pFF1, const float* __restrict__ bff1,
    const unsigned short* __restrict__ pFF2, const float* __restrict__ bff2,
    const float* __restrict__ ln3s, const float* __restrict__ ln3b,
    const unsigned short* __restrict__ pHead, const float* __restrict__ bhead,
    const float* __restrict__ xin, float* __restrict__ xout,
    const int* __restrict__ steps, int s) {
  if (s >= *steps) return;
  __shared__ float lbuf[16][132];           // attn-out -> ln2(y2) -> y3 -> ln3(y3)
  __shared__ float ly2[16][132];            // y2 (residual for FF2)
  __shared__ unsigned short lh[16][520];    // GELU(FF1) bf16
  __shared__ float lmean[16], lrstd[16], lmask[16];
  const int t = threadIdx.x;
  const int base = blockIdx.x * 16;
  const int w = t >> 6, l = t & 63;
  const int lr = (l >> 4) * 4;              // D-frag row base
  const int lc = l & 15;                    // D-frag col within tile

  if (t < 16) { // stochastic per-cell mask (JAX threefry, partitionable bits)
    uint32_t kk0, kk1, b0, b1;
    tf2x32(0u, 42u, 0u, (uint32_t)s, kk0, kk1);
    tf2x32(kk0, kk1, 0u, (uint32_t)(base + t), b0, b1);
    uint32_t bits = b0 ^ b1;
    lmask[t] = ((bits >> 9) > 0x400000u) ? 1.0f : 0.0f;
  }
  // ---- attention: 16 cells x 8 heads x 2 subs(8 elems) = 256 threads ----
  {
    const int cell = t >> 4, head = (t >> 1) & 7, sub = t & 1;
    const int n = base + cell;
    const int dd = n % 24, ww = (n / 24) % 24, hh = n / 576;
    float qf[8];
    bf8_to_f(qkv + (size_t)n * 384 + head * 16 + sub * 8, qf);
    float logits[27];
    int idx = 0;
    #pragma unroll
    for (int di = -1; di <= 1; ++di)
    #pragma unroll
    for (int dj = -1; dj <= 1; ++dj)
    #pragma unroll
    for (int dk = -1; dk <= 1; ++dk) {
      int h2 = hh + di, w2 = ww + dj, d2 = dd + dk;
      bool ok = ((unsigned)h2 < 24u) && ((unsigned)w2 < 24u) && ((unsigned)d2 < 24u);
      float dot = 0.f;
      if (ok) {
        float kf[8];
        bf8_to_f(qkv + (size_t)((h2 * 24 + w2) * 24 + d2) * 384 + 128 + head * 16 + sub * 8, kf);
        #pragma unroll
        for (int j = 0; j < 8; ++j) dot += qf[j] * kf[j];
      }
      dot += __shfl_xor(dot, 1);            // combine the two 8-elem halves
      logits[idx++] = dot * 0.25f;          // OOB -> logit 0 (zero-padded localize)
    }
    float m = logits[0];
    #pragma unroll
    for (int j = 1; j < 27; ++j) m = fmaxf(m, logits[j]);
    float den = 0.f;
    #pragma unroll
    for (int j = 0; j < 27; ++j) { logits[j] = expf(logits[j] - m); den += logits[j]; }
    float av[8];
    #pragma unroll
    for (int j = 0; j < 8; ++j) av[j] = 0.f;
    idx = 0;
    #pragma unroll
    for (int di = -1; di <= 1; ++di)
    #pragma unroll
    for (int dj = -1; dj <= 1; ++dj)
    #pragma unroll
    for (int dk = -1; dk <= 1; ++dk) {
      int h2 = hh + di, w2 = ww + dj, d2 = dd + dk;
      bool ok = ((unsigned)h2 < 24u) && ((unsigned)w2 < 24u) && ((unsigned)d2 < 24u);
      if (ok) {
        float vf[8];
        bf8_to_f(qkv + (size_t)((h2 * 24 + w2) * 24 + d2) * 384 + 256 + head * 16 + sub * 8, vf);
        float wgt = logits[idx];
        #pragma unroll
        for (int j = 0; j < 8; ++j) av[j] += wgt * vf[j];
      }
      ++idx;
    }
    float inv = 1.f / den;
    #pragma unroll
    for (int j = 0; j < 8; ++j) lbuf[cell][head * 16 + sub * 8 + j] = av[j] * inv;
  }
  __syncthreads();
  // ---- out-proj GEMM 16x128, K=128; wave w: coltiles w*2, w*2+1 ----
  bf16x8 a4[4];
  #pragma unroll
  for (int kt = 0; kt < 4; ++kt)
    a4[kt] = afrag_f32(&lbuf[l & 15][kt * 32 + (l >> 4) * 8]);
  {
    f32x4 acc[2];
    acc[0] = (f32x4){0.f,0.f,0.f,0.f}; acc[1] = (f32x4){0.f,0.f,0.f,0.f};
    const bf16x8* B = (const bf16x8*)pOut;
    #pragma unroll
    for (int kt = 0; kt < 4; ++kt) {
      #pragma unroll
      for (int q = 0; q < 2; ++q) {
        int nt = w * 2 + q;
        bf16x8 b = B[(nt * 4 + kt) * 64 + l];
        acc[q] = __builtin_amdgcn_mfma_f32_16x16x32_bf16(a4[kt], b, acc[q], 0, 0, 0);
      }
    }
    __syncthreads();  // all frag reads of lbuf done
    #pragma unroll
    for (int q = 0; q < 2; ++q) {
      int col = (w * 2 + q) * 16 + lc;
      #pragma unroll
      for (int j = 0; j < 4; ++j) {
        int r = lr + j;
        int n = base + r;
        float res = (col < 126) ? xin[(size_t)n * 128 + col] : pe_val(n, col);
        ly2[r][col] = acc[q][j] + bout[col] + res;
      }
    }
  }
  __syncthreads();
  { // LN2 stats
    int r = t >> 4, j = t & 15;
    float s1 = 0.f, s2 = 0.f;
    #pragma unroll
    for (int cc = 0; cc < 8; ++cc) { float v = ly2[r][j * 8 + cc]; s1 += v; s2 += v * v; }
    #pragma unroll
    for (int off = 1; off < 16; off <<= 1) { s1 += __shfl_xor(s1, off); s2 += __shfl_xor(s2, off); }
    if (j == 0) {
      float m = s1 * (1.f / 128.f);
      float var = s2 * (1.f / 128.f) - m * m;
      lmean[r] = m; lrstd[r] = rsqrtf(var + 1e-5f);
    }
  }
  __syncthreads();
  #pragma unroll
  for (int i = 0; i < 8; ++i) {
    int idx = i * 256 + t;
    int r = idx >> 7, c = idx & 127;
    lbuf[r][c] = (ly2[r][c] - lmean[r]) * lrstd[r] * ln2s[c] + ln2b[c];
  }
  __syncthreads();
  // ---- FF1 GEMM 16x512, K=128; wave w: coltiles w*8..w*8+7; GELU -> lh bf16 ----
  #pragma unroll
  for (int kt = 0; kt < 4; ++kt)
    a4[kt] = afrag_f32(&lbuf[l & 15][kt * 32 + (l >> 4) * 8]);
  {
    f32x4 acc[8];
    #pragma unroll
    for (int q = 0; q < 8; ++q) acc[q] = (f32x4){0.f,0.f,0.f,0.f};
    const bf16x8* B = (const bf16x8*)pFF1;
    #pragma unroll
    for (int kt = 0; kt < 4; ++kt) {
      #pragma unroll
      for (int q = 0; q < 8; ++q) {
        int nt = w * 8 + q;
        bf16x8 b = B[(nt * 4 + kt) * 64 + l];
        acc[q] = __builtin_amdgcn_mfma_f32_16x16x32_bf16(a4[kt], b, acc[q], 0, 0, 0);
      }
    }
    #pragma unroll
    for (int q = 0; q < 8; ++q) {
      int col = (w * 8 + q) * 16 + lc;
      #pragma unroll
      for (int j = 0; j < 4; ++j) {
        float v = acc[q][j] + bff1[col];
        v = 0.5f * v * (1.f + erff(v * 0.70710678118654752f));
        lh[lr + j][col] = f2bf(v);
      }
    }
  }
  __syncthreads();
  // ---- FF2 GEMM 16x128, K=512 ----
  f32x4 acc3[2];
  acc3[0] = (f32x4){0.f,0.f,0.f,0.f}; acc3[1] = (f32x4){0.f,0.f,0.f,0.f};
  {
    const bf16x8* B = (const bf16x8*)pFF2;
    #pragma unroll
    for (int kt = 0; kt < 16; ++kt) {
      bf16x8 a = *(const bf16x8*)&lh[l & 15][kt * 32 + (l >> 4) * 8];
      #pragma unroll
      for (int q = 0; q < 2; ++q) {
        int nt = w * 2 + q;
        bf16x8 b = B[(nt * 16 + kt) * 64 + l];
        acc3[q] = __builtin_amdgcn_mfma_f32_16x16x32_bf16(a, b, acc3[q], 0, 0, 0);
      }
    }
  }
  __syncthreads();  // lbuf (ln2) fully consumed
  #pragma unroll
  for (int q = 0; q < 2; ++q) {
    int col = (w * 2 + q) * 16 + lc;
    #pragma unroll
    for (int j = 0; j < 4; ++j) {
      int r = lr + j;
      lbuf[r][col] = acc3[q][j] + bff2[col] + ly2[r][col];  // y3
    }
  }
  __syncthreads();
  { // LN3 stats
    int r = t >> 4, j = t & 15;
    float s1 = 0.f, s2 = 0.f;
    #pragma unroll
    for (int cc = 0; cc < 8; ++cc) { float v = lbuf[r][j * 8 + cc]; s1 += v; s2 += v * v; }
    #pragma unroll
    for (int off = 1; off < 16; off <<= 1) { s1 += __shfl_xor(s1, off); s2 += __shfl_xor(s2, off); }
    if (j == 0) {
      float m = s1 * (1.f / 128.f);
      float var = s2 * (1.f / 128.f) - m * m;
      lmean[r] = m; lrstd[r] = rsqrtf(var + 1e-5f);
    }
  }
  __syncthreads();
  #pragma unroll
  for (int i = 0; i < 8; ++i) {
    int idx = i * 256 + t;
    int r = idx >> 7, c = idx & 127;
    lbuf[r][c] = (lbuf[r][c] - lmean[r]) * lrstd[r] * ln3s[c] + ln3b[c];
  }
  __syncthreads();
  // ---- head GEMM 16x128, K=128 -> dx; masked residual update ----
  #pragma unroll
  for (int kt = 0; kt < 4; ++kt)
    a4[kt] = afrag_f32(&lbuf[l & 15][kt * 32 + (l >> 4) * 8]);
  {
    f32x4 acc[2];
    acc[0] = (f32x4){0.f,0.f,0.f,0.f}; acc[1] = (f32x4){0.f,0.f,0.f,0.f};
    const bf16x8* B = (const bf16x8*)pHead;
    #pragma unroll
    for (int kt = 0; kt < 4; ++kt) {
      #pragma unroll
      for (int q = 0; q < 2; ++q) {
        int nt = w * 2 + q;
        bf16x8 b = B[(nt * 4 + kt) * 64 + l];
        acc[q] = __builtin_amdgcn_mfma_f32_16x16x32_bf16(a4[kt], b, acc[q], 0, 0, 0);
      }
    }
    #pragma unroll
    for (int q = 0; q < 2; ++q) {
      int col = (w * 2 + q) * 16 + lc;
      #pragma unroll
      for (int j = 0; j < 4; ++j) {
        int r = lr + j;
        size_t n = base + r;
        float dx = acc[q][j] + bhead[col];
        xout[n * 128 + col] = xin[n * 128 + col] + dx * lmask[r];
      }
    }
  }
}

extern "C" void kernel_launch(void* const* d_in, const int* in_sizes, int n_in,
                              void* d_out, int out_size, void* d_ws, size_t ws_size,
                              hipStream_t stream) {
  const float* x0   = (const float*)d_in[0];
  const float* Wqkv = (const float*)d_in[1];
  const float* Wout = (const float*)d_in[2];
  const float* bout = (const float*)d_in[3];
  const float* ln1s = (const float*)d_in[4];
  const float* ln1b = (const float*)d_in[5];
  const float* Wff1 = (const float*)d_in[6];
  const float* bff1 = (const float*)d_in[7];
  const float* Wff2 = (const float*)d_in[8];
  const float* bff2 = (const float*)d_in[9];
  const float* ln2s = (const float*)d_in[10];
  const float* ln2b = (const float*)d_in[11];
  const float* ln3s = (const float*)d_in[12];
  const float* ln3b = (const float*)d_in[13];
  const float* Whead= (const float*)d_in[14];
  const float* bhead= (const float*)d_in[15];
  const int*   steps= (const int*)d_in[16];
  float* out = (float*)d_out;

  unsigned short* wqkv = (unsigned short*)d_ws;          // N*384 bf16
  unsigned short* pQkv = wqkv + (size_t)NCELL * 384;
  unsigned short* pOut = pQkv + 128 * 384;
  unsigned short* pFF1 = pOut + 128 * 128;
  unsigned short* pFF2 = pFF1 + 128 * 512;
  unsigned short* pHead= pFF2 + 512 * 128;

  packAll<<<dim3(104), dim3(256), 0, stream>>>(Wqkv, Wout, Wff1, Wff2, Whead,
                                               pQkv, pOut, pFF1, pFF2, pHead);
  for (int s = 0; s < 2; ++s) {
    const float* xin = (s == 0) ? x0 : out;
    nca_k1<<<dim3(864), dim3(256), 0, stream>>>(xin, ln1s, ln1b, pQkv, wqkv, steps, s);
    nca_k2f<<<dim3(864), dim3(256), 0, stream>>>(wqkv, pOut, bout, ln2s, ln2b,
                                                 pFF1, bff1, pFF2, bff2, ln3s, ln3b,
                                                 pHead, bhead, xin, out, steps, s);
  }
}